// Round 7
// baseline (155.288 us; speedup 1.0000x reference)
//
#include <hip/hip_runtime.h>
#include <hip/hip_fp16.h>
#include <math.h>

// Problem constants (B=8, S=2048, T=128)
#define S_LEN 2048
#define T_DIM 128
#define BM 128               // tokens per block (m-range): Mt=4 m-tiles
#define TN 64                // output cols per block: Nt=2 t-tiles
#define NBLK 256             // (mb 0..127) x (th 0..1); th on bit0 -> XCD-pinned
#define TOKR 132             // tokT2 row stride in f16 (264 B)

typedef _Float16 half8 __attribute__((ext_vector_type(8)));
typedef _Float16 half4t __attribute__((ext_vector_type(4)));
typedef float floatx16 __attribute__((ext_vector_type(16)));

// Fast exact tanh: 1 - 2/(1+e^{2x})
__device__ __forceinline__ float tanh_fast(float x) {
  return 1.0f - __fdividef(2.0f, 1.0f + __expf(2.0f * x));
}

// ---------------------------------------------------------------------------
// Kernel A (grid 3072x256): fused prep:
//  blocks 0..1023  : W fp32 [t][p][q] -> W16f fp16 MFMA-fragment order
//  blocks 1024..3071: out[b,i,t] = Sw*tanh(b_comp[t]) + b_red  (prefill)
//  R7 additions: per-(b,i) contributor counts (16K atomics into ws) + Sw stash.
// ---------------------------------------------------------------------------
__global__ __launch_bounds__(256) void prep_kernel(
    const float* __restrict__ W, const float* __restrict__ w_red,
    const float* __restrict__ b_comp, const float* __restrict__ b_red,
    const int* __restrict__ heads,
    _Float16* __restrict__ W16f, float* __restrict__ out,
    int* counts, float* swslot) {
  const int blk = blockIdx.x;
  const int tid = threadIdx.x;
  if (blk < 1024) {
    const int t = blk >> 3;
    const int qh = (blk >> 2) & 1;
    const int it = blk & 3;
    const int tc = t >> 5, tl = t & 31;
    const int e8 = it * 256 + tid;        // 0..1023 over [p(128)][q-chunk(8)]
    const int p = e8 >> 3;
    const int q = qh * 64 + (e8 & 7) * 8;
    const float* src = W + (size_t)t * 16384 + (size_t)p * 128 + q;
    const float4 v0 = *(const float4*)src;
    const float4 v1 = *(const float4*)(src + 4);
    half8 h;
    h[0] = (_Float16)v0.x; h[1] = (_Float16)v0.y;
    h[2] = (_Float16)v0.z; h[3] = (_Float16)v0.w;
    h[4] = (_Float16)v1.x; h[5] = (_Float16)v1.y;
    h[6] = (_Float16)v1.z; h[7] = (_Float16)v1.w;
    const int kc = q >> 4, lh2 = (q >> 3) & 1;
    *(half8*)(W16f + ((size_t)((p * 4 + tc) * 8 + kc)) * 512 + lh2 * 256 + tl * 8) = h;
  } else {
    __shared__ float red4[4];
    const int blk2 = blk - 1024;          // 0..2047
    // contributor counting: 8 tokens per block, 16K atomics total
    if (counts != nullptr && tid < 8) {
      const int gm = blk2 * 8 + tid;      // global token index 0..16383
      atomicAdd(&counts[(gm >> 11) * 2048 + heads[gm]], 1);
    }
    float part = 0.f;
#pragma unroll
    for (int i = 0; i < 8; ++i) part += w_red[i * 256 + tid];   // coalesced
#pragma unroll
    for (int off = 32; off > 0; off >>= 1) part += __shfl_down(part, off, 64);
    if ((tid & 63) == 0) red4[tid >> 6] = part;
    __syncthreads();
    const float Sw = red4[0] + red4[1] + red4[2] + red4[3];
    if (swslot != nullptr && blk2 == 0 && tid == 0) swslot[0] = Sw;
    const float br = b_red[0];
    const size_t base = (size_t)blk2 * 1024 + (size_t)tid * 4;
    const int t0 = (int)(base & 127);
    float4 v;
    v.x = Sw * tanh_fast(b_comp[t0 + 0]) + br;
    v.y = Sw * tanh_fast(b_comp[t0 + 1]) + br;
    v.z = Sw * tanh_fast(b_comp[t0 + 2]) + br;
    v.w = Sw * tanh_fast(b_comp[t0 + 3]) + br;
    *(float4*)(out + base) = v;
  }
}

// ---------------------------------------------------------------------------
// Kernel B: MFMA main, BM=128 x TN=64 (Mt=4, Nt=2). Loop = R3 verbatim
// (best measured; 5 loop restructures R2-R6 all null => loop not the wall).
// R7 THEORY: the hidden ~35-40us is the SERIAL post-loop phase:
//  (a) kh-reduction was 4 barrier-serialized phases -> now 2 (tokT2 dead
//      after the loop, so alias FOUR 32KB planes in 128KB LDS; even waves
//      write, odd waves add).
//  (b) epilogue issued 8192 device-scope atomicAdds per block (2M chip-wide,
//      L2/fabric RMW-serialized; R1's 2-block/CU null is consistent: all
//      blocks storm atomics simultaneously at the end). With random heads,
//      ~63% of tokens are the SOLE contributor to their head row chip-wide:
//      prep counts contributors per (b,i); cnt==1 rows take a plain store
//      of base+delta (no RMW), others keep atomicAdd.
// v_mfma_f32_32x32x16_f16: A lane m=l&31, k=(l>>5)*8+j; B n=l&31 same k;
// C/D col=l&31, row=(r&3)+8*(r>>2)+4*(l>>5)   [m74/m101-verified]
// ---------------------------------------------------------------------------
__global__ __launch_bounds__(512, 2) void main_kernel(
    const float* __restrict__ tok, const int* __restrict__ heads,
    const _Float16* __restrict__ W16f, const float* __restrict__ b_comp,
    const float* __restrict__ w_red, const float* __restrict__ b_red,
    const int* __restrict__ cnts, const float* __restrict__ swsl,
    const int use_cnt, float* __restrict__ out) {
  __shared__ __align__(16) char smem[131072]; // 128 KB: tokT2 (34K) / 4 planes
  _Float16* const tokT2 = (_Float16*)smem;    // [p][(mi ^ swz(p))]
  float* const planes = (float*)smem;         // 4 x 8192 floats, post-loop

  const int tid = threadIdx.x;
  const int lane = tid & 63;
  const int kh = tid >> 6;   // wave = q-chunk of 16 (kc index)
  const int l31 = lane & 31;
  const int lh = lane >> 5;
  const int blk = blockIdx.x;
  const int th = blk & 1;                 // t-half, bit0 (XCD-pinned: XCD=blk&7)
  const int mb = blk >> 1;                // 0..127
  // Full-rank p-phase stagger per XCD (R1-proven L2 decorrelation)
  const int pstag = ((blk >> 3) * 4) & 127;
  const size_t tokbase = (size_t)mb * BM * T_DIM;

  // Wave's B-fragment offsets: tc = th*2 + tt, kc = kh
  int off[2];
#pragma unroll
  for (int tt = 0; tt < 2; ++tt)
    off[tt] = (((th * 2 + tt) * 8 + kh) << 9) + lane * 8;

  half8 bf0[2], bf1[2], bf2[2];
  half4t tk0, tk1, tk2;
  half8 h16[4];

  auto loadB = [&](half8 (&bf)[2], int p) {
    const int pp = (p + pstag) & 127;
    const _Float16* wp = W16f + (size_t)pp * 16384;
    bf[0] = *(const half8*)(wp + off[0]);
    bf[1] = *(const half8*)(wp + off[1]);
  };
  auto loadT = [&](half4t& tk, int p) {
    const int pp = (p + pstag) & 127;
    const int col = (l31 * 4) ^ (((pp + (pp >> 3)) & 7) << 2);
    tk = *(const half4t*)(tokT2 + pp * TOKR + col);
  };

  // First two W16f fragment loads issue before the barrier: L2 latency
  // overlaps the LDS staging drain.
  loadB(bf0, 0);
  loadB(bf1, 1);

  // ---- stage tokT2: coalesced float4 reads, swizzled transposed f16 writes --
#pragma unroll
  for (int it = 0; it < 8; ++it) {
    const int f = it * 512 + tid;   // 0..4095 float4s over [m(128)][p4(32)]
    const int m = f >> 5;
    const int p0 = (f & 31) * 4;
    const float4 v = *(const float4*)(tok + tokbase + (size_t)m * 128 + p0);
    const int mi = (m & 31) * 4 + (m >> 5);
    const float vv[4] = {v.x, v.y, v.z, v.w};
#pragma unroll
    for (int jj = 0; jj < 4; ++jj) {
      const int p = p0 + jj;
      const int col = mi ^ (((p + (p >> 3)) & 7) << 2);
      tokT2[p * TOKR + col] = (_Float16)vv[jj];
    }
  }

  // ---- per-lane h fragments: h16[mh], m = mh*32 + l31, q0 = kh*16 + lh*8 ----
#pragma unroll
  for (int mh = 0; mh < 4; ++mh) {
    const int m = mh * 32 + l31;
    const int q0 = kh * 16 + lh * 8;
    const float4 v0 = *(const float4*)(tok + tokbase + (size_t)m * 128 + q0);
    const float4 v1 = *(const float4*)(tok + tokbase + (size_t)m * 128 + q0 + 4);
    h16[mh][0] = (_Float16)tanh_fast(v0.x);
    h16[mh][1] = (_Float16)tanh_fast(v0.y);
    h16[mh][2] = (_Float16)tanh_fast(v0.z);
    h16[mh][3] = (_Float16)tanh_fast(v0.w);
    h16[mh][4] = (_Float16)tanh_fast(v1.x);
    h16[mh][5] = (_Float16)tanh_fast(v1.y);
    h16[mh][6] = (_Float16)tanh_fast(v1.z);
    h16[mh][7] = (_Float16)tanh_fast(v1.w);
  }

  floatx16 acc[4][2];  // [mh][tt] -> 128 AGPRs
#pragma unroll
  for (int mh = 0; mh < 4; ++mh)
#pragma unroll
    for (int tt = 0; tt < 2; ++tt)
#pragma unroll
      for (int r = 0; r < 16; ++r) acc[mh][tt][r] = 0.f;

  __syncthreads();  // tokT2 ready; last barrier before the p-loop

  auto compute = [&](half8 (&bf)[2], half4t tk) {
#pragma unroll
    for (int mh = 0; mh < 4; ++mh) {
      half8 a = h16[mh] * tk[mh];   // 4 v_pk_mul each, feeds 2 MFMA
      acc[mh][0] = __builtin_amdgcn_mfma_f32_32x32x16_f16(a, bf[0], acc[mh][0], 0, 0, 0);
      acc[mh][1] = __builtin_amdgcn_mfma_f32_32x32x16_f16(a, bf[1], acc[mh][1], 0, 0, 0);
    }
  };

  // 3-buffer, distance-2 software pipeline over 128 p (no barriers).
  loadT(tk0, 0);
  loadT(tk1, 1);
  for (int p = 0; p < 126; p += 3) {
    loadB(bf2, p + 2);  loadT(tk2, p + 2);
    compute(bf0, tk0);
    loadB(bf0, p + 3);  loadT(tk0, p + 3);
    compute(bf1, tk1);
    loadB(bf1, p + 4);  loadT(tk1, p + 4);
    compute(bf2, tk2);
  }
  compute(bf0, tk0);  // p = 126
  compute(bf1, tk1);  // p = 127

  // ---- kh reduction: 4 planes (alias tokT2), 2 serial phases ----
  __syncthreads();   // all tk reads done; planes may now overwrite tokT2
  {
    float* P = planes + (kh >> 1) * (BM * TN);
    const int ph = kh & 1;
    if (ph == 0) {
#pragma unroll
      for (int mh = 0; mh < 4; ++mh)
#pragma unroll
        for (int tt = 0; tt < 2; ++tt) {
          const int t_loc = tt * 32 + l31;
#pragma unroll
          for (int r = 0; r < 16; ++r) {
            const int m_loc = mh * 32 + (r & 3) + 8 * (r >> 2) + 4 * lh;
            P[m_loc * TN + t_loc] = acc[mh][tt][r];
          }
        }
    }
    __syncthreads();
    if (ph == 1) {
#pragma unroll
      for (int mh = 0; mh < 4; ++mh)
#pragma unroll
        for (int tt = 0; tt < 2; ++tt) {
          const int t_loc = tt * 32 + l31;
#pragma unroll
          for (int r = 0; r < 16; ++r) {
            const int m_loc = mh * 32 + (r & 3) + 8 * (r >> 2) + 4 * lh;
            P[m_loc * TN + t_loc] += acc[mh][tt][r];
          }
        }
    }
    __syncthreads();
  }

  // ---- scatter epilogue: cnt==1 rows -> plain store; else atomicAdd ----
  const int t_loc = tid & 63;
  const int mgrp = tid >> 6;  // 0..7 (wave-uniform -> scalar heads/w_red loads)
  const int t = th * 64 + t_loc;
  const float bc = b_comp[t];
  const float tb = tanh_fast(bc);
  const float brv = b_red[0];
  const float Swv = use_cnt ? swsl[0] : 0.f;
  const float base_t = Swv * tb + brv;   // prefill value for this t
#pragma unroll 4
  for (int mi = 0; mi < 16; ++mi) {
    const int m_loc = mi * 8 + mgrp;
    const int gm = mb * BM + m_loc;
    const int head = heads[gm];
    const float wr = w_red[gm & 2047];
    const int a = m_loc * TN + t_loc;
    const float v = planes[a] + planes[BM * TN + a] + planes[2 * BM * TN + a] +
                    planes[3 * BM * TN + a] + bc;
    const float val = wr * (tanh_fast(v) - tb);
    const int row = (gm >> 11) * 2048 + head;
    float* dst = out + (size_t)row * T_DIM + t;
    if (use_cnt && cnts[row] == 1) {
      *dst = base_t + val;               // sole contributor: no RMW needed
    } else {
      atomicAdd(dst, val);
    }
  }
}

// ---------------------------------------------------------------------------
extern "C" void kernel_launch(void* const* d_in, const int* in_sizes, int n_in,
                              void* d_out, int out_size, void* d_ws, size_t ws_size,
                              hipStream_t stream) {
  const float* tok    = (const float*)d_in[0];
  // d_in[1] = dep_embeddings: dead input (source bug), unused
  const int*   heads  = (const int*)d_in[2];
  const float* W      = (const float*)d_in[3];
  const float* b_comp = (const float*)d_in[4];
  const float* w_red  = (const float*)d_in[5];
  const float* b_red  = (const float*)d_in[6];
  float* out = (float*)d_out;

  _Float16* W16f = (_Float16*)d_ws;  // 4 MB, MFMA-fragment order

  const size_t W16_BYTES = 4u * 1024u * 1024u;
  const size_t CNT_BYTES = 8u * 2048u * sizeof(int);       // 64 KB
  const size_t need = W16_BYTES + CNT_BYTES + 16;
  const int use_cnt = (ws_size >= need) ? 1 : 0;
  int*   counts = use_cnt ? (int*)((char*)d_ws + W16_BYTES) : nullptr;
  float* swslot = use_cnt ? (float*)((char*)d_ws + W16_BYTES + CNT_BYTES) : nullptr;

  if (use_cnt) hipMemsetAsync(counts, 0, CNT_BYTES, stream);
  prep_kernel<<<3072, 256, 0, stream>>>(W, w_red, b_comp, b_red, heads,
                                        W16f, out, counts, swslot);
  main_kernel<<<NBLK, 512, 0, stream>>>(tok, heads, W16f, b_comp, w_red, b_red,
                                        counts, swslot, use_cnt, out);
}

// Round 8
// 154.313 us; speedup vs baseline: 1.0063x; 1.0063x over previous
//
#include <hip/hip_runtime.h>
#include <hip/hip_fp16.h>
#include <math.h>

// Problem constants (B=8, S=2048, T=128)
#define S_LEN 2048
#define T_DIM 128
#define BM 128               // tokens per block (m-range): Mt=4 m-tiles
#define TN 64                // output cols per block: Nt=2 t-tiles
#define NBLK 256             // (mb 0..127) x (th 0..1); th on bit0 -> XCD-pinned
#define TOKR 132             // tokT2 row stride in f16 (264 B)
#define SLOT0 34816          // byte offset of W-slot region in smem
// smem: [0,34816) tokT2 | [34816, 34816+3*32768) W slots (3 x 32KB) = 130KB

typedef _Float16 half8 __attribute__((ext_vector_type(8)));
typedef _Float16 half4t __attribute__((ext_vector_type(4)));
typedef float floatx16 __attribute__((ext_vector_type(16)));
typedef unsigned int u32;

// Fast exact tanh: 1 - 2/(1+e^{2x})
__device__ __forceinline__ float tanh_fast(float x) {
  return 1.0f - __fdividef(2.0f, 1.0f + __expf(2.0f * x));
}

// global->LDS DMA, 16B/lane, dest = wave-uniform base + lane*16 (HW rule)
__device__ __forceinline__ void load_lds16(const void* g, void* l) {
  __builtin_amdgcn_global_load_lds(
      (const __attribute__((address_space(1))) u32*)g,
      (__attribute__((address_space(3))) u32*)l, 16, 0, 0);
}

// ---------------------------------------------------------------------------
// Kernel A (grid 3072x256): fused prep (R6 form):
//  blocks 0..1023  : W fp32 [t][p][q] -> W16f fp16 MFMA-fragment order
//  blocks 1024..3071: out[b,i,t] = Sw*tanh(b_comp[t]) + b_red  (prefill)
// ---------------------------------------------------------------------------
__global__ __launch_bounds__(256) void prep_kernel(
    const float* __restrict__ W, const float* __restrict__ w_red,
    const float* __restrict__ b_comp, const float* __restrict__ b_red,
    _Float16* __restrict__ W16f, float* __restrict__ out) {
  const int blk = blockIdx.x;
  const int tid = threadIdx.x;
  if (blk < 1024) {
    const int t = blk >> 3;
    const int qh = (blk >> 2) & 1;
    const int it = blk & 3;
    const int tc = t >> 5, tl = t & 31;
    const int e8 = it * 256 + tid;        // 0..1023 over [p(128)][q-chunk(8)]
    const int p = e8 >> 3;
    const int q = qh * 64 + (e8 & 7) * 8;
    const float* src = W + (size_t)t * 16384 + (size_t)p * 128 + q;
    const float4 v0 = *(const float4*)src;
    const float4 v1 = *(const float4*)(src + 4);
    half8 h;
    h[0] = (_Float16)v0.x; h[1] = (_Float16)v0.y;
    h[2] = (_Float16)v0.z; h[3] = (_Float16)v0.w;
    h[4] = (_Float16)v1.x; h[5] = (_Float16)v1.y;
    h[6] = (_Float16)v1.z; h[7] = (_Float16)v1.w;
    const int kc = q >> 4, lh2 = (q >> 3) & 1;
    *(half8*)(W16f + ((size_t)((p * 4 + tc) * 8 + kc)) * 512 + lh2 * 256 + tl * 8) = h;
  } else {
    __shared__ float red4[4];
    float part = 0.f;
#pragma unroll
    for (int i = 0; i < 8; ++i) part += w_red[i * 256 + tid];   // coalesced
#pragma unroll
    for (int off = 32; off > 0; off >>= 1) part += __shfl_down(part, off, 64);
    if ((tid & 63) == 0) red4[tid >> 6] = part;
    __syncthreads();
    const float Sw = red4[0] + red4[1] + red4[2] + red4[3];
    const float br = b_red[0];
    const size_t base = (size_t)(blk - 1024) * 1024 + (size_t)tid * 4;
    const int t0 = (int)(base & 127);
    float4 v;
    v.x = Sw * tanh_fast(b_comp[t0 + 0]) + br;
    v.y = Sw * tanh_fast(b_comp[t0 + 1]) + br;
    v.z = Sw * tanh_fast(b_comp[t0 + 2]) + br;
    v.w = Sw * tanh_fast(b_comp[t0 + 3]) + br;
    *(float4*)(out + base) = v;
  }
}

// ---------------------------------------------------------------------------
// Kernel B: MFMA main, BM=128 x TN=64, BARRIER-PACED 2-p PHASES (R8).
// R8 THEORY: seven falsifications = exact replica of learn_hip m131-m141's
// "~900 TF simple-loop ceiling" on this chip; the only measured escape is
// the block-paced phase schedule (m194-m218: +28-41%; counted-vmcnt within
// it +38-73%, m218; setprio pays ONLY there, m218b). Port: 64 phases of
// 2 p-steps. Per phase:
//   stage(ph+2): 4x global_load_lds(16B) -> wave-private LDS slot
//   s_waitcnt vmcnt(4)   [counted: ph+1's DMAs done, ph+2's stay in flight;
//                         never 0 in steady loop]
//   s_barrier + sched_barrier(0)   [pacing; raw barrier, NO vmcnt drain]
//   ds_read bf(ph+1) 4x b128 + tk(ph+1) 2x b64   [slot (ph+1)%3]
//   setprio(1); 16 MFMA (phase ph: a built in-cluster, bf from regs);
//   setprio(0)
// Slots wave-private (kh stages exactly the kc=kh fragments it consumes) =>
// zero cross-wave deps; barriers are pure pacing. LDS 130KB: tokT2 34K +
// 3x32K slots; red planes alias [0,64K) post-loop. 1 blk/CU, 2 waves/SIMD.
// vmcnt invariant: at PHASE(j) wait, outstanding = (j+1)'s 4 + (j+2)'s 4
// => vmcnt(4) completes (j+1)'s. Tail ph62: vmcnt(0) (only 63's remain).
// v_mfma_f32_32x32x16_f16: A lane m=l&31, k=(l>>5)*8+j; B n=l&31 same k;
// C/D col=l&31, row=(r&3)+8*(r>>2)+4*(l>>5)   [m74/m101-verified]
// ---------------------------------------------------------------------------
__global__ __launch_bounds__(512, 2) void main_kernel(
    const float* __restrict__ tok, const int* __restrict__ heads,
    const _Float16* __restrict__ W16f, const float* __restrict__ b_comp,
    const float* __restrict__ w_red, float* __restrict__ out) {
  __shared__ __align__(16) char smem[133120];  // 130 KB
  _Float16* const tokT2 = (_Float16*)smem;     // [p][(mi ^ swz(p))]
  float* const red0 = (float*)smem;            // epilogue alias, plane 0 (32 KB)
  float* const red1 = (float*)(smem + 32768);  // plane 1 (32 KB)

  const int tid = threadIdx.x;
  const int lane = tid & 63;
  const int kh = tid >> 6;   // wave = q-chunk of 16 (kc index)
  const int l31 = lane & 31;
  const int lh = lane >> 5;
  const int blk = blockIdx.x;
  const int th = blk & 1;                 // t-half, bit0 (XCD-pinned: XCD=blk&7)
  const int mb = blk >> 1;                // 0..127
  const int pstag = ((blk >> 3) * 4) & 127;  // L2 decorrelation (R1-proven)
  const size_t tokbase = (size_t)mb * BM * T_DIM;

  // Wave-private slot base (4KB per wave per slot) + DMA lane source base
  char* const myslot = smem + SLOT0 + kh * 4096;          // + s*32768 + chunk
  const char* const wsrc = (const char*)W16f + (size_t)lane * 16;

  half8 h16[4];
  floatx16 acc[4][2];  // [mh][tt] -> 128 AGPRs

  // stage phase ph's 2 p-slabs (kc=kh fragments only) into slot s
  auto stage = [&](int ph, int s) {
#pragma unroll
    for (int i = 0; i < 2; ++i) {
      const int pp = (ph * 2 + i + pstag) & 127;
#pragma unroll
      for (int tt = 0; tt < 2; ++tt) {
        const size_t gb = ((size_t)((pp * 4 + th * 2 + tt) * 8 + kh)) * 1024;
        load_lds16(wsrc + gb, myslot + s * 32768 + (i * 2 + tt) * 1024);
      }
    }
  };
  auto readBF = [&](half8 (&bf)[2][2], int s) {
#pragma unroll
    for (int i = 0; i < 2; ++i)
#pragma unroll
      for (int tt = 0; tt < 2; ++tt)
        bf[i][tt] = *(const half8*)(myslot + s * 32768 + (i * 2 + tt) * 1024 + lane * 16);
  };
  auto readTK = [&](half4t (&tk)[2], int ph) {
#pragma unroll
    for (int i = 0; i < 2; ++i) {
      const int pp = (ph * 2 + i + pstag) & 127;
      const int col = (l31 * 4) ^ (((pp + (pp >> 3)) & 7) << 2);
      tk[i] = *(const half4t*)(tokT2 + pp * TOKR + col);
    }
  };
  auto cluster = [&](half8 (&bf)[2][2], half4t (&tk)[2]) {
    __builtin_amdgcn_s_setprio(1);
#pragma unroll
    for (int i = 0; i < 2; ++i)
#pragma unroll
      for (int mh = 0; mh < 4; ++mh) {
        half8 a = h16[mh] * tk[i][mh];   // 4 pk_mul, feeds 2 MFMA
        acc[mh][0] = __builtin_amdgcn_mfma_f32_32x32x16_f16(a, bf[i][0], acc[mh][0], 0, 0, 0);
        acc[mh][1] = __builtin_amdgcn_mfma_f32_32x32x16_f16(a, bf[i][1], acc[mh][1], 0, 0, 0);
      }
    __builtin_amdgcn_s_setprio(0);
  };

  // ---- prologue: issue slot 0/1 DMAs first (hide under staging) ----
  stage(0, 0);
  stage(1, 1);

  // ---- stage tokT2: coalesced float4 reads, swizzled transposed f16 writes --
#pragma unroll
  for (int it = 0; it < 8; ++it) {
    const int f = it * 512 + tid;   // 0..4095 float4s over [m(128)][p4(32)]
    const int m = f >> 5;
    const int p0 = (f & 31) * 4;
    const float4 v = *(const float4*)(tok + tokbase + (size_t)m * 128 + p0);
    const int mi = (m & 31) * 4 + (m >> 5);
    const float vv[4] = {v.x, v.y, v.z, v.w};
#pragma unroll
    for (int jj = 0; jj < 4; ++jj) {
      const int p = p0 + jj;
      const int col = mi ^ (((p + (p >> 3)) & 7) << 2);
      tokT2[p * TOKR + col] = (_Float16)vv[jj];
    }
  }

  // ---- per-lane h fragments: h16[mh], m = mh*32 + l31, q0 = kh*16 + lh*8 ----
#pragma unroll
  for (int mh = 0; mh < 4; ++mh) {
    const int m = mh * 32 + l31;
    const int q0 = kh * 16 + lh * 8;
    const float4 v0 = *(const float4*)(tok + tokbase + (size_t)m * 128 + q0);
    const float4 v1 = *(const float4*)(tok + tokbase + (size_t)m * 128 + q0 + 4);
    h16[mh][0] = (_Float16)tanh_fast(v0.x);
    h16[mh][1] = (_Float16)tanh_fast(v0.y);
    h16[mh][2] = (_Float16)tanh_fast(v0.z);
    h16[mh][3] = (_Float16)tanh_fast(v0.w);
    h16[mh][4] = (_Float16)tanh_fast(v1.x);
    h16[mh][5] = (_Float16)tanh_fast(v1.y);
    h16[mh][6] = (_Float16)tanh_fast(v1.z);
    h16[mh][7] = (_Float16)tanh_fast(v1.w);
  }

#pragma unroll
  for (int mh = 0; mh < 4; ++mh)
#pragma unroll
    for (int tt = 0; tt < 2; ++tt)
#pragma unroll
      for (int r = 0; r < 16; ++r) acc[mh][tt][r] = 0.f;

  __syncthreads();  // tokT2 ready; full drain => slots 0,1 complete

  half8 bfA[2][2], bfB[2][2];
  half4t tkA[2], tkB[2];
  readBF(bfA, 0);
  readTK(tkA, 0);

  // Phase PH: stage(PH+2)->S_STAGE; vmcnt(4); barrier; read PH+1 from S_READ;
  // MFMA cluster for PH (operands read/built in earlier phases).
#define PHASE(PH, S_STAGE, S_READ, BFC, TKC, BFN, TKN)   \
  {                                                      \
    stage((PH) + 2, S_STAGE);                            \
    asm volatile("s_waitcnt vmcnt(4)" ::: "memory");     \
    __builtin_amdgcn_s_barrier();                        \
    __builtin_amdgcn_sched_barrier(0);                   \
    readBF(BFN, S_READ);                                 \
    readTK(TKN, (PH) + 1);                               \
    cluster(BFC, TKC);                                   \
  }
  for (int ph = 0; ph < 60; ph += 6) {
    PHASE(ph + 0, 2, 1, bfA, tkA, bfB, tkB);
    PHASE(ph + 1, 0, 2, bfB, tkB, bfA, tkA);
    PHASE(ph + 2, 1, 0, bfA, tkA, bfB, tkB);
    PHASE(ph + 3, 2, 1, bfB, tkB, bfA, tkA);
    PHASE(ph + 4, 0, 2, bfA, tkA, bfB, tkB);
    PHASE(ph + 5, 1, 0, bfB, tkB, bfA, tkA);
  }
  PHASE(60, 2, 1, bfA, tkA, bfB, tkB);   // stage 62->slot2, read 61<-slot1
  PHASE(61, 0, 2, bfB, tkB, bfA, tkA);   // stage 63->slot0, read 62<-slot2
#undef PHASE
  // ph=62: no stage left; only 63's DMAs outstanding
  asm volatile("s_waitcnt vmcnt(0)" ::: "memory");
  __builtin_amdgcn_s_barrier();
  __builtin_amdgcn_sched_barrier(0);
  readBF(bfB, 0);
  readTK(tkB, 63);
  cluster(bfA, tkA);   // phase 62
  cluster(bfB, tkB);   // phase 63

  // ---- kh reduction: parity -> plane, 4 serial phases (2 waves/phase) ----
  // (red planes alias tokT2/slot0; barrier orders all loop reads before)
  __syncthreads();
  {
    float* R = (kh & 1) ? red1 : red0;
    const int g = kh >> 1;
#pragma unroll
    for (int phase = 0; phase < 4; ++phase) {
      if (g == phase) {
#pragma unroll
        for (int mh = 0; mh < 4; ++mh)
#pragma unroll
          for (int tt = 0; tt < 2; ++tt) {
            const int t_loc = tt * 32 + l31;
#pragma unroll
            for (int r = 0; r < 16; ++r) {
              const int m_loc = mh * 32 + (r & 3) + 8 * (r >> 2) + 4 * lh;
              const int addr = m_loc * TN + t_loc;
              if (phase == 0) R[addr] = acc[mh][tt][r];
              else            R[addr] += acc[mh][tt][r];
            }
          }
      }
      __syncthreads();
    }
  }

  // ---- inline scatter epilogue: 512 threads, 16 m's x 1 t each ----
  const int t_loc = tid & 63;
  const int mgrp = tid >> 6;  // 0..7 (wave-uniform -> scalar heads/w_red loads)
  const int t = th * 64 + t_loc;
  const float bc = b_comp[t];
  const float tb = tanh_fast(bc);
#pragma unroll 4
  for (int mi = 0; mi < 16; ++mi) {
    const int m_loc = mi * 8 + mgrp;
    const int gm = mb * BM + m_loc;
    const int head = heads[gm];
    const float wr = w_red[gm & 2047];
    const float v = red0[m_loc * TN + t_loc] + red1[m_loc * TN + t_loc] + bc;
    atomicAdd(out + ((size_t)(gm >> 11) * S_LEN + head) * T_DIM + t,
              wr * (tanh_fast(v) - tb));
  }
}

// ---------------------------------------------------------------------------
extern "C" void kernel_launch(void* const* d_in, const int* in_sizes, int n_in,
                              void* d_out, int out_size, void* d_ws, size_t ws_size,
                              hipStream_t stream) {
  const float* tok    = (const float*)d_in[0];
  // d_in[1] = dep_embeddings: dead input (source bug), unused
  const int*   heads  = (const int*)d_in[2];
  const float* W      = (const float*)d_in[3];
  const float* b_comp = (const float*)d_in[4];
  const float* w_red  = (const float*)d_in[5];
  const float* b_red  = (const float*)d_in[6];
  float* out = (float*)d_out;

  _Float16* W16f = (_Float16*)d_ws;  // 4 MB, MFMA-fragment order

  prep_kernel<<<3072, 256, 0, stream>>>(W, w_red, b_comp, b_red, W16f, out);
  main_kernel<<<NBLK, 512, 0, stream>>>(tok, heads, W16f, b_comp, w_red, out);
}

// Round 10
// 148.117 us; speedup vs baseline: 1.0484x; 1.0418x over previous
//
#include <hip/hip_runtime.h>
#include <hip/hip_fp16.h>
#include <math.h>

// Problem constants (B=8, S=2048, T=128)
#define S_LEN 2048
#define T_DIM 128
#define BM 128               // tokens per block (m-range): Mt=4 m-tiles
#define TN 64                // output cols per block: Nt=2 t-tiles
#define NBLK 256             // (mb 0..127) x (th 0..1); th on bit0 -> XCD-pinned
#define TOKR 132             // tokT2 row stride in f16 (264 B)
#define TOK_BYTES 33792      // 128 * TOKR * 2 exactly

typedef _Float16 half8 __attribute__((ext_vector_type(8)));
typedef _Float16 half4t __attribute__((ext_vector_type(4)));
typedef float floatx16 __attribute__((ext_vector_type(16)));

// Fast exact tanh: 1 - 2/(1+e^{2x})
__device__ __forceinline__ float tanh_fast(float x) {
  return 1.0f - __fdividef(2.0f, 1.0f + __expf(2.0f * x));
}

// ---------------------------------------------------------------------------
// Kernel A — R9 rewrite, re-run (R10): coalesced transform + 8x-dedup prefill.
//  blocks 0..511 (tc 0..3 x p 0..127): thread (kc=tid>>5, tl=tid&31) reads
//    64B contiguous W[t=tc*32+tl][p][kc*16..+16), writes half8 pairs so each
//    wave writes each 1KB fragment fully contiguously:
//    W16f[((p*4+tc)*8+kc)*512 + {0,256} + tl*8]  (== old lh2*256+tl*8 layout).
//  blocks 512..767: prefill out; float4 value depends only on t=(tid*4)&127,
//    computed once, stored 8x at 4KB stride (32KB/block).
// Same arithmetic as the R3-era prep -> bit-identical outputs.
// ---------------------------------------------------------------------------
__global__ __launch_bounds__(256) void prep_kernel(
    const float* __restrict__ W, const float* __restrict__ w_red,
    const float* __restrict__ b_comp, const float* __restrict__ b_red,
    _Float16* __restrict__ W16f, float* __restrict__ out) {
  const int blk = blockIdx.x;
  const int tid = threadIdx.x;
  if (blk < 512) {
    const int p = blk & 127;
    const int tc = blk >> 7;          // 0..3
    const int kc = tid >> 5;          // 0..7
    const int tl = tid & 31;
    const int t = tc * 32 + tl;
    const float* src = W + (size_t)t * 16384 + (size_t)p * 128 + kc * 16;
    const float4 a = *(const float4*)(src);
    const float4 b = *(const float4*)(src + 4);
    const float4 c = *(const float4*)(src + 8);
    const float4 d = *(const float4*)(src + 12);
    half8 lo, hi;
    lo[0] = (_Float16)a.x; lo[1] = (_Float16)a.y;
    lo[2] = (_Float16)a.z; lo[3] = (_Float16)a.w;
    lo[4] = (_Float16)b.x; lo[5] = (_Float16)b.y;
    lo[6] = (_Float16)b.z; lo[7] = (_Float16)b.w;
    hi[0] = (_Float16)c.x; hi[1] = (_Float16)c.y;
    hi[2] = (_Float16)c.z; hi[3] = (_Float16)c.w;
    hi[4] = (_Float16)d.x; hi[5] = (_Float16)d.y;
    hi[6] = (_Float16)d.z; hi[7] = (_Float16)d.w;
    _Float16* fb = W16f + ((size_t)((p * 4 + tc) * 8 + kc)) * 512;
    *(half8*)(fb + tl * 8) = lo;         // lanes 0-31: contiguous 512 B
    *(half8*)(fb + 256 + tl * 8) = hi;   // second 512 B half, contiguous
  } else {
    __shared__ float red4[4];
    float part = 0.f;
#pragma unroll
    for (int i = 0; i < 8; ++i) part += w_red[i * 256 + tid];   // coalesced
#pragma unroll
    for (int off = 32; off > 0; off >>= 1) part += __shfl_down(part, off, 64);
    if ((tid & 63) == 0) red4[tid >> 6] = part;
    __syncthreads();
    const float Sw = red4[0] + red4[1] + red4[2] + red4[3];
    const float br = b_red[0];
    const int t0 = (tid * 4) & 127;      // invariant across the 8 stores
    float4 v;
    v.x = Sw * tanh_fast(b_comp[t0 + 0]) + br;
    v.y = Sw * tanh_fast(b_comp[t0 + 1]) + br;
    v.z = Sw * tanh_fast(b_comp[t0 + 2]) + br;
    v.w = Sw * tanh_fast(b_comp[t0 + 3]) + br;
    float* dst = out + (size_t)(blk - 512) * 8192 + (size_t)tid * 4;
#pragma unroll
    for (int k = 0; k < 8; ++k) *(float4*)(dst + k * 1024) = v;
  }
}

// ---------------------------------------------------------------------------
// Kernel B: MFMA main, BM=128 x TN=64 (Mt=4, Nt=2) — R3 VERBATIM except the
// R10 fix: red planes at byte offsets 33792 / 66560 (R9 mistakenly used
// 34816 -> red1's last 1KB wrote past the 99328-byte LDS block = UB =
// absmax 4.3e-2). Total is exactly 33792 + 2*32768 = 99328.
// R2-R8 established the loop is insensitive to tile shape, pipeline medium
// & depth, dependency decoupling, wave de-phasing, reduction/atomic
// restructure, and barrier-paced counted-vmcnt phases (all 72-82us).
// v_mfma_f32_32x32x16_f16: A lane m=l&31, k=(l>>5)*8+j; B n=l&31 same k;
// C/D col=l&31, row=(r&3)+8*(r>>2)+4*(l>>5)   [m74/m101-verified]
// ---------------------------------------------------------------------------
__global__ __launch_bounds__(512, 2) void main_kernel(
    const float* __restrict__ tok, const int* __restrict__ heads,
    const _Float16* __restrict__ W16f, const float* __restrict__ b_comp,
    const float* __restrict__ w_red, float* __restrict__ out) {
  __shared__ __align__(16) char smembuf[99328];   // tokT2 33792 + red 2x32768
  _Float16* const tokT2 = (_Float16*)smembuf;     // [p][(mi ^ swz(p))]
  float* const red0 = (float*)(smembuf + TOK_BYTES);
  float* const red1 = (float*)(smembuf + TOK_BYTES + 32768);

  const int tid = threadIdx.x;
  const int lane = tid & 63;
  const int kh = tid >> 6;   // wave = q-chunk of 16 (kc index)
  const int l31 = lane & 31;
  const int lh = lane >> 5;
  const int blk = blockIdx.x;
  const int th = blk & 1;                 // t-half, bit0 (XCD-pinned: XCD=blk&7)
  const int mb = blk >> 1;                // 0..127
  // Full-rank p-phase stagger per XCD (R1-proven L2 decorrelation)
  const int pstag = ((blk >> 3) * 4) & 127;
  const size_t tokbase = (size_t)mb * BM * T_DIM;

  // Wave's B-fragment offsets: tc = th*2 + tt, kc = kh
  int off[2];
#pragma unroll
  for (int tt = 0; tt < 2; ++tt)
    off[tt] = (((th * 2 + tt) * 8 + kh) << 9) + lane * 8;

  half8 bf0[2], bf1[2], bf2[2];
  half4t tk0, tk1, tk2;
  half8 h16[4];

  auto loadB = [&](half8 (&bf)[2], int p) {
    const int pp = (p + pstag) & 127;
    const _Float16* wp = W16f + (size_t)pp * 16384;
    bf[0] = *(const half8*)(wp + off[0]);
    bf[1] = *(const half8*)(wp + off[1]);
  };
  auto loadT = [&](half4t& tk, int p) {
    const int pp = (p + pstag) & 127;
    const int col = (l31 * 4) ^ (((pp + (pp >> 3)) & 7) << 2);
    tk = *(const half4t*)(tokT2 + pp * TOKR + col);
  };

  // First two W16f fragment loads issue before the barrier: L2 latency
  // overlaps the LDS staging drain.
  loadB(bf0, 0);
  loadB(bf1, 1);

  // ---- stage tokT2: coalesced float4 reads, swizzled transposed f16 writes --
#pragma unroll
  for (int it = 0; it < 8; ++it) {
    const int f = it * 512 + tid;   // 0..4095 float4s over [m(128)][p4(32)]
    const int m = f >> 5;
    const int p0 = (f & 31) * 4;
    const float4 v = *(const float4*)(tok + tokbase + (size_t)m * 128 + p0);
    const int mi = (m & 31) * 4 + (m >> 5);
    const float vv[4] = {v.x, v.y, v.z, v.w};
#pragma unroll
    for (int jj = 0; jj < 4; ++jj) {
      const int p = p0 + jj;
      const int col = mi ^ (((p + (p >> 3)) & 7) << 2);
      tokT2[p * TOKR + col] = (_Float16)vv[jj];
    }
  }

  // ---- per-lane h fragments: h16[mh], m = mh*32 + l31, q0 = kh*16 + lh*8 ----
#pragma unroll
  for (int mh = 0; mh < 4; ++mh) {
    const int m = mh * 32 + l31;
    const int q0 = kh * 16 + lh * 8;
    const float4 v0 = *(const float4*)(tok + tokbase + (size_t)m * 128 + q0);
    const float4 v1 = *(const float4*)(tok + tokbase + (size_t)m * 128 + q0 + 4);
    h16[mh][0] = (_Float16)tanh_fast(v0.x);
    h16[mh][1] = (_Float16)tanh_fast(v0.y);
    h16[mh][2] = (_Float16)tanh_fast(v0.z);
    h16[mh][3] = (_Float16)tanh_fast(v0.w);
    h16[mh][4] = (_Float16)tanh_fast(v1.x);
    h16[mh][5] = (_Float16)tanh_fast(v1.y);
    h16[mh][6] = (_Float16)tanh_fast(v1.z);
    h16[mh][7] = (_Float16)tanh_fast(v1.w);
  }

  floatx16 acc[4][2];  // [mh][tt] -> 128 AGPRs
#pragma unroll
  for (int mh = 0; mh < 4; ++mh)
#pragma unroll
    for (int tt = 0; tt < 2; ++tt)
#pragma unroll
      for (int r = 0; r < 16; ++r) acc[mh][tt][r] = 0.f;

  __syncthreads();  // tokT2 ready; last barrier before the p-loop

  auto compute = [&](half8 (&bf)[2], half4t tk) {
#pragma unroll
    for (int mh = 0; mh < 4; ++mh) {
      half8 a = h16[mh] * tk[mh];   // 4 v_pk_mul each, feeds 2 MFMA
      acc[mh][0] = __builtin_amdgcn_mfma_f32_32x32x16_f16(a, bf[0], acc[mh][0], 0, 0, 0);
      acc[mh][1] = __builtin_amdgcn_mfma_f32_32x32x16_f16(a, bf[1], acc[mh][1], 0, 0, 0);
    }
  };

  // 3-buffer, distance-2 software pipeline over 128 p (no barriers).
  loadT(tk0, 0);
  loadT(tk1, 1);
  for (int p = 0; p < 126; p += 3) {
    loadB(bf2, p + 2);  loadT(tk2, p + 2);
    compute(bf0, tk0);
    loadB(bf0, p + 3);  loadT(tk0, p + 3);
    compute(bf1, tk1);
    loadB(bf1, p + 4);  loadT(tk1, p + 4);
    compute(bf2, tk2);
  }
  compute(bf0, tk0);  // p = 126
  compute(bf1, tk1);  // p = 127

  // ---- kh reduction: parity -> plane, 4 serial phases (2 waves/phase) ----
  __syncthreads();
  {
    float* R = (kh & 1) ? red1 : red0;
    const int g = kh >> 1;
#pragma unroll
    for (int phase = 0; phase < 4; ++phase) {
      if (g == phase) {
#pragma unroll
        for (int mh = 0; mh < 4; ++mh)
#pragma unroll
          for (int tt = 0; tt < 2; ++tt) {
            const int t_loc = tt * 32 + l31;
#pragma unroll
            for (int r = 0; r < 16; ++r) {
              const int m_loc = mh * 32 + (r & 3) + 8 * (r >> 2) + 4 * lh;
              const int addr = m_loc * TN + t_loc;
              if (phase == 0) R[addr] = acc[mh][tt][r];
              else            R[addr] += acc[mh][tt][r];
            }
          }
      }
      __syncthreads();
    }
  }

  // ---- inline scatter epilogue: 512 threads, 16 m's x 1 t each ----
  const int t_loc = tid & 63;
  const int mgrp = tid >> 6;  // 0..7 (wave-uniform -> scalar heads/w_red loads)
  const int t = th * 64 + t_loc;
  const float bc = b_comp[t];
  const float tb = tanh_fast(bc);
#pragma unroll 4
  for (int mi = 0; mi < 16; ++mi) {
    const int m_loc = mi * 8 + mgrp;
    const int gm = mb * BM + m_loc;
    const int head = heads[gm];
    const float wr = w_red[gm & 2047];
    const float v = red0[m_loc * TN + t_loc] + red1[m_loc * TN + t_loc] + bc;
    atomicAdd(out + ((size_t)(gm >> 11) * S_LEN + head) * T_DIM + t,
              wr * (tanh_fast(v) - tb));
  }
}

// ---------------------------------------------------------------------------
extern "C" void kernel_launch(void* const* d_in, const int* in_sizes, int n_in,
                              void* d_out, int out_size, void* d_ws, size_t ws_size,
                              hipStream_t stream) {
  const float* tok    = (const float*)d_in[0];
  // d_in[1] = dep_embeddings: dead input (source bug), unused
  const int*   heads  = (const int*)d_in[2];
  const float* W      = (const float*)d_in[3];
  const float* b_comp = (const float*)d_in[4];
  const float* w_red  = (const float*)d_in[5];
  const float* b_red  = (const float*)d_in[6];
  float* out = (float*)d_out;

  _Float16* W16f = (_Float16*)d_ws;  // 4 MB, MFMA-fragment order

  prep_kernel<<<768, 256, 0, stream>>>(W, w_red, b_comp, b_red, W16f, out);
  main_kernel<<<NBLK, 512, 0, stream>>>(tok, heads, W16f, b_comp, w_red, out);
}